// Round 7
// baseline (328.759 us; speedup 1.0000x reference)
//
#include <hip/hip_runtime.h>

#define BATCH 16
#define CCH 512
#define LEN 4096
#define LPAD 4098

typedef unsigned short u16;
typedef __bf16 bf16x8 __attribute__((ext_vector_type(8)));
typedef float f32x4 __attribute__((ext_vector_type(4)));
typedef u16 u16x8 __attribute__((ext_vector_type(8)));
typedef u16 u16x4 __attribute__((ext_vector_type(4)));

__device__ __forceinline__ u16 f2bf(float f) {
    unsigned u = __float_as_uint(f);
    u = (u + 0x7fffu + ((u >> 16) & 1u)) >> 16;
    return (u16)u;
}
__device__ __forceinline__ float bf2f(u16 v) {
    return __uint_as_float(((unsigned)v) << 16);
}
__device__ __forceinline__ float silu_f(float v) {
    return v / (1.f + __expf(-v));
}
__device__ __forceinline__ void async16(const u16* g, u16* l) {
    __builtin_amdgcn_global_load_lds(
        (const __attribute__((address_space(1))) unsigned int*)g,
        (__attribute__((address_space(3))) unsigned int*)l, 16, 0, 0);
}

#define SBAR() __builtin_amdgcn_sched_barrier(0)
#define HWBAR() { SBAR(); __builtin_amdgcn_s_barrier(); SBAR(); }
#define WAIT_LGKM0() { asm volatile("s_waitcnt lgkmcnt(0)" ::: "memory"); SBAR(); }
#define WAIT_VM(n) { asm volatile("s_waitcnt vmcnt(" #n ")" ::: "memory"); SBAR(); }

// ---------------------------------------------------------------------------
__global__ __launch_bounds__(256)
void absmean_partial(const float* __restrict__ w1, const float* __restrict__ w2,
                     float* __restrict__ part) {
    const int tid = threadIdx.x;
    const int base = blockIdx.x * 3072;
    float s1 = 0.f, s2 = 0.f;
    for (int i = tid; i < 3072; i += 256) {
        s1 += fabsf(w1[base + i]);
        s2 += fabsf(w2[base + i]);
    }
    __shared__ float r1[256], r2[256];
    r1[tid] = s1; r2[tid] = s2;
    __syncthreads();
    for (int off = 128; off > 0; off >>= 1) {
        if (tid < off) { r1[tid] += r1[tid + off]; r2[tid] += r2[tid + off]; }
        __syncthreads();
    }
    if (tid == 0) { part[blockIdx.x] = r1[0]; part[256 + blockIdx.x] = r2[0]; }
}

__global__ __launch_bounds__(256)
void finalize_scale(const float* __restrict__ part, float* __restrict__ sv) {
    const int tid = threadIdx.x;
    __shared__ float r1[256], r2[256];
    r1[tid] = part[tid]; r2[tid] = part[256 + tid];
    __syncthreads();
    for (int off = 128; off > 0; off >>= 1) {
        if (tid < off) { r1[tid] += r1[tid + off]; r2[tid] += r2[tid + off]; }
        __syncthreads();
    }
    if (tid == 0) {
        sv[0] = fmaxf(r1[0] * (1.f / 786432.f), 1e-5f);
        sv[1] = fmaxf(r2[0] * (1.f / 786432.f), 1e-5f);
    }
}

// ---------------------------------------------------------------------------
__global__ __launch_bounds__(256)
void quantize_w(const float* __restrict__ w, const float* __restrict__ sv,
                int sidx, u16* __restrict__ wqt) {
    const int idx = blockIdx.x * 256 + threadIdx.x;
    const float s = sv[sidx];
    float q = rintf(w[idx] / s);
    q = fmaxf(-1.f, fminf(1.f, q));
    const int o   = idx / 1536;
    const int rem = idx - o * 1536;
    const int i   = rem / 3;
    const int k   = rem - i * 3;
    wqt[k * (CCH * CCH) + o * CCH + i] = f2bf(q);
}

__global__ __launch_bounds__(256)
void zero_pads(u16* __restrict__ h, u16* __restrict__ h1) {
    const int idx = blockIdx.x * 256 + threadIdx.x;   // [0, 16384)
    const int b = idx >> 10;
    const int r = (idx >> 9) & 1;
    const int i = idx & 511;
    const size_t off = ((size_t)b * LPAD + (r ? (LPAD - 1) : 0)) * CCH + i;
    h[off] = 0;
    h1[off] = 0;
}

// ---------------------------------------------------------------------------
__global__ __launch_bounds__(256)
void rms_silu_transpose(const float* __restrict__ x, const float* __restrict__ g,
                        u16* __restrict__ h_t) {
    __shared__ u16   xt[CCH][33];
    __shared__ float red[8][32];
    __shared__ float rinv[32];
    const int tid = threadIdx.x;
    const int bb  = blockIdx.x >> 7;
    const int l0  = (blockIdx.x & 127) << 5;

    const size_t xbase = (size_t)bb * CCH * LEN + l0;
    {
        const int i_hi = tid >> 3;
        const int l4   = (tid & 7) << 2;
        #pragma unroll
        for (int it = 0; it < 16; ++it) {
            const int i = it * 32 + i_hi;
            const float4 v = *(const float4*)&x[xbase + (size_t)i * LEN + l4];
            xt[i][l4 + 0] = f2bf(v.x);
            xt[i][l4 + 1] = f2bf(v.y);
            xt[i][l4 + 2] = f2bf(v.z);
            xt[i][l4 + 3] = f2bf(v.w);
        }
    }
    __syncthreads();
    {
        const int l = tid & 31, seg = tid >> 5;
        const int ibeg = seg * 64;
        float ss = 0.f;
        #pragma unroll 8
        for (int i = ibeg; i < ibeg + 64; ++i) {
            const float v = bf2f(xt[i][l]);
            ss += v * v;
        }
        red[seg][l] = ss;
    }
    __syncthreads();
    if (tid < 32) {
        float tot = 0.f;
        #pragma unroll
        for (int k2 = 0; k2 < 8; ++k2) tot += red[k2][tid];
        rinv[tid] = rsqrtf(tot * (1.f / 512.f) + 1e-6f);
    }
    __syncthreads();
    {
        const int l  = tid >> 3;
        const int i0 = (tid & 7) << 6;
        const float ri = rinv[l];
        const size_t ob = ((size_t)bb * LPAD + l0 + l + 1) * CCH + i0;
        for (int ii = 0; ii < 64; ii += 8) {
            u16x8 ov;
            #pragma unroll
            for (int jj = 0; jj < 8; ++jj) {
                const int i = i0 + ii + jj;
                float v = bf2f(xt[i][l]) * ri * g[i];
                ov[jj] = f2bf(silu_f(v));
            }
            *(u16x8*)&h_t[ob + ii] = ov;
        }
    }
}

// ---------------------------------------------------------------------------
// Conv-as-GEMM, 256x128 tile, BK=32, TRIPLE-buffered LDS (72 KiB -> 2 blocks
// per CU = two desynchronized barrier domains).  512 threads = 8 waves (4Mx2N),
// per-wave 64x64 (4x4 frags, acc=64).  Prefetch depth 2, counted vmcnt(3).
// K order ks-inner: t -> (ks=t%3, i0=(t/3)*32).  T1 XCD chunk, T2 swizzle, T5.
template<int EPI>
__global__ __launch_bounds__(512)
void conv_gemm8(const u16* __restrict__ Bsrc, const u16* __restrict__ Wq,
                const float* __restrict__ sptr, const float* __restrict__ bias,
                const float* __restrict__ resid, u16* __restrict__ outb,
                float* __restrict__ outf) {
    extern __shared__ u16 lds[];          // 36864 u16 = 72 KiB (3 x 12288)
    const int tid  = threadIdx.x;
    const int lane = tid & 63;
    const int wave = tid >> 6;
    const int wm = wave >> 1;             // 0..3  (M quarter, 64 rows)
    const int wn = wave & 1;              // 0..1  (N half, 64 cols)

    // T1: bijective XCD chunking (1024 = 8 x 128); mt-pairs share a B-panel.
    const int wgid = (blockIdx.x & 7) * 128 + (blockIdx.x >> 3);
    const int mt = wgid & 1;
    const int nt = wgid >> 1;             // 0..511
    const int o0 = mt << 8;               // 0 or 256
    const int bb = nt >> 5;               // 0..15
    const int l0 = (nt & 31) << 7;        // 0..3968 (128-wide N tile)

    // staging: row = tid>>2 (0..127), col chunk q = tid&3 (8 u16), swizzled
    const int sr   = tid >> 2;
    const int scol = ((tid & 3) << 3) ^ ((sr & 3) << 3);   // pre-swizzled src col
    const int sdst = tid << 3;                             // u16 in 4096-u16 round

    const u16* aSrcBase = Wq + (size_t)(o0 + sr) * CCH + scol;
    const u16* bSrcBase = Bsrc + ((size_t)bb * LPAD + l0 + sr) * CCH + scol;

    // stage K-step t into buffer pb: A 256x32 (2 rounds) + B 128x32 (1 round)
    auto stage_full = [&](int pb, int t) {
        const int ks = t % 3;
        const int i0 = (t / 3) << 5;
        const u16* wsrc = aSrcBase + ks * (CCH * CCH) + i0;
        async16(wsrc, &lds[pb * 12288 + sdst]);
        async16(wsrc + 128 * CCH, &lds[pb * 12288 + 4096 + sdst]);
        async16(bSrcBase + (size_t)ks * CCH + i0, &lds[pb * 12288 + 8192 + sdst]);
    };

    // ds_read geometry: row r holds k-cols ((q<<3)^((r&3)<<3)); reader wants
    // k-offset (lane>>4)*8 -> col = ((lane>>4)^(lane&3))<<3  (row%4 == lane%4)
    const int cc = (((lane >> 4) ^ (lane & 3)) << 3);
    const int aOff = (wm * 64 + (lane & 15)) * 32 + cc;           // A region
    const int bOff = 8192 + (wn * 64 + (lane & 15)) * 32 + cc;    // B region

    f32x4 acc[4][4];
    #pragma unroll
    for (int m = 0; m < 4; ++m)
        #pragma unroll
        for (int n = 0; n < 4; ++n)
            acc[m][n] = (f32x4){0.f, 0.f, 0.f, 0.f};

    // prologue: stage t0 -> buf0, t1 -> buf1; wait t0 (3 loads of t1 in flight)
    stage_full(0, 0);
    stage_full(1, 1);
    WAIT_VM(3);
    HWBAR();

    int pb = 0;
    for (int t = 0; t < 48; ++t) {
        const int cb = pb * 12288;
        const bool full = (t < 46);
        if (full) stage_full((pb + 2) % 3, t + 2);      // prefetch depth 2
        bf16x8 ar[4], br[4];
        #pragma unroll
        for (int m = 0; m < 4; ++m)
            ar[m] = *(const bf16x8*)&lds[cb + aOff + m * 512];
        #pragma unroll
        for (int n = 0; n < 4; ++n)
            br[n] = *(const bf16x8*)&lds[cb + bOff + n * 512];
        __builtin_amdgcn_s_setprio(1);
        #pragma unroll
        for (int m = 0; m < 4; ++m)
            #pragma unroll
            for (int n = 0; n < 4; ++n)
                acc[m][n] = __builtin_amdgcn_mfma_f32_16x16x32_bf16(
                    ar[m], br[n], acc[m][n], 0, 0, 0);
        __builtin_amdgcn_s_setprio(0);
        WAIT_LGKM0();                  // this buf's reads retired (WAR safety)
        if (full) { WAIT_VM(3); } else { WAIT_VM(0); }   // next buf landed
        HWBAR();
        pb = (pb + 1) % 3;
    }

    // epilogue
    const float sc = sptr[0];

    if (EPI == 1) {
        // silu(sc*acc+bias) -> LDS [l_loc 0..127][o_loc 0..255] bf16 swizzled,
        // then coalesced 16B stores (4 lanes fill one 64B sector).
        #pragma unroll
        for (int m = 0; m < 4; ++m) {
            const int o_loc = wm * 64 + m * 16 + ((lane >> 4) << 2);
            const int ob = o0 + o_loc;
            const float b0 = bias[ob + 0], b1 = bias[ob + 1];
            const float b2 = bias[ob + 2], b3 = bias[ob + 3];
            #pragma unroll
            for (int n = 0; n < 4; ++n) {
                const int l_loc = wn * 64 + n * 16 + (lane & 15);
                const f32x4 a = acc[m][n];
                u16x4 ov;
                ov[0] = f2bf(silu_f(sc * a[0] + b0));
                ov[1] = f2bf(silu_f(sc * a[1] + b1));
                ov[2] = f2bf(silu_f(sc * a[2] + b2));
                ov[3] = f2bf(silu_f(sc * a[3] + b3));
                char* p = (char*)lds + l_loc * 512 +
                          (((unsigned)(o_loc << 1)) ^ ((l_loc & 7) << 4));
                *(u16x4*)p = ov;
            }
        }
        __syncthreads();
        const int l_r = tid >> 2;            // 0..127
        const int oq  = (tid & 3) << 3;      // u16: 0,8,16,24
        u16* gdst = outb + ((size_t)bb * LPAD + l0 + l_r + 1) * CCH + o0 + oq;
        char* srp = (char*)lds + l_r * 512;
        const int swz2 = (l_r & 7) << 4;
        #pragma unroll
        for (int c = 0; c < 8; ++c) {
            const uint4 v = *(const uint4*)(srp + (((oq << 1) + c * 64) ^ swz2));
            *(uint4*)(gdst + c * 32) = v;
        }
    } else {
        const int lbase = l0 + wn * 64 + (lane & 15);
        const int obase = o0 + wm * 64 + ((lane >> 4) << 2);
        #pragma unroll
        for (int m = 0; m < 4; ++m) {
            const int ob = obase + m * 16;
            #pragma unroll
            for (int n = 0; n < 4; ++n) {
                const int l = lbase + n * 16;
                const f32x4 a = acc[m][n];
                #pragma unroll
                for (int jj = 0; jj < 4; ++jj) {
                    const size_t idx = ((size_t)bb * CCH + (ob + jj)) * LEN + l;
                    outf[idx] = sc * a[jj] + bias[ob + jj] + resid[idx];
                }
            }
        }
    }
}

// ---------------------------------------------------------------------------
extern "C" void kernel_launch(void* const* d_in, const int* in_sizes, int n_in,
                              void* d_out, int out_size, void* d_ws, size_t ws_size,
                              hipStream_t stream) {
    const float* x  = (const float*)d_in[0];
    const float* w1 = (const float*)d_in[1];
    const float* b1 = (const float*)d_in[2];
    const float* w2 = (const float*)d_in[3];
    const float* b2 = (const float*)d_in[4];
    const float* g  = (const float*)d_in[5];
    float* out = (float*)d_out;

    char* ws = (char*)d_ws;
    float* sv   = (float*)ws;
    float* part = (float*)(ws + 256);
    u16* wq1   = (u16*)(ws + 4096);
    u16* wq2   = (u16*)(ws + 4096 + 1572864);
    u16* h_t   = (u16*)(ws + 4096 + 2 * 1572864);                 // [16][4098][512] bf16
    u16* h1_t  = (u16*)(ws + 4096 + 2 * 1572864 + 67141632);      // [16][4098][512] bf16

    hipFuncSetAttribute((const void*)conv_gemm8<1>,
                        hipFuncAttributeMaxDynamicSharedMemorySize, 73728);
    hipFuncSetAttribute((const void*)conv_gemm8<2>,
                        hipFuncAttributeMaxDynamicSharedMemorySize, 73728);

    absmean_partial<<<dim3(256), dim3(256), 0, stream>>>(w1, w2, part);
    finalize_scale<<<dim3(1), dim3(256), 0, stream>>>(part, sv);
    quantize_w<<<dim3(3072), dim3(256), 0, stream>>>(w1, sv, 0, wq1);
    quantize_w<<<dim3(3072), dim3(256), 0, stream>>>(w2, sv, 1, wq2);
    zero_pads<<<dim3(64), dim3(256), 0, stream>>>(h_t, h1_t);
    rms_silu_transpose<<<dim3(2048), dim3(256), 0, stream>>>(x, g, h_t);
    conv_gemm8<1><<<dim3(1024), dim3(512), 73728, stream>>>(h_t, wq1, sv, b1,
                                                            nullptr, h1_t, nullptr);
    conv_gemm8<2><<<dim3(1024), dim3(512), 73728, stream>>>(h1_t, wq2, sv + 1, b2,
                                                            x, nullptr, out);
}